// Round 1
// baseline (721.999 us; speedup 1.0000x reference)
//
#include <hip/hip_runtime.h>
#include <stdint.h>

// Batched Viterbi decode: B=8192, T=512, K=12.
// Layout: 16 lanes per batch row (12 active tag-lanes j=0..11, 4 pad).
// Forward: per step, gather the 12 prev trellis values via ds_bpermute within
// the 16-lane group, compute best/argmax per tag, store backpointer byte.
// Backtrack: fused, lane j==0 of each group walks its own bp stream backward.
//
// Output buffer = [scores: B floats][paths: B*T floats (tag as float)].

namespace {

constexpr int kB = 8192;
constexpr int kT = 512;
constexpr int kK = 12;
constexpr int kSlot = 12; // bytes per (b,t) backpointer record

__global__ __launch_bounds__(256) void viterbi_fused(
    const float* __restrict__ logits,   // [B, T, K]
    const float* __restrict__ trans,    // [K, K]
    float* __restrict__ out,            // [B] scores + [B*T] paths
    uint8_t* __restrict__ bp)           // [B, T-1, kSlot]
{
    const int tid  = blockIdx.x * blockDim.x + threadIdx.x;
    const int b    = tid >> 4;
    const int j    = tid & 15;
    const int jeff = (j < kK) ? j : (kK - 1);
    const int lane = threadIdx.x & 63;
    const int gbase = lane & 48;        // 16-lane group base within wave

    // Preload transitions column jeff: Tcol[i] = trans[i][jeff]
    float Tcol[kK];
#pragma unroll
    for (int i = 0; i < kK; ++i) Tcol[i] = trans[i * kK + jeff];

    const float* em = logits + (size_t)b * kT * kK;
    uint8_t* bpb = bp + (size_t)b * (kT - 1) * kSlot;

    float prev = em[jeff];              // trellis init = emissions at t=0

    for (int t = 1; t < kT; ++t) {
        const float emit = em[t * kK + jeff];

        // gather prev[0..11] from the group's tag lanes
        float p[kK];
#pragma unroll
        for (int i = 0; i < kK; ++i) {
            p[i] = __int_as_float(
                __builtin_amdgcn_ds_bpermute((gbase + i) << 2,
                                             __float_as_int(prev)));
        }

        float best = p[0] + Tcol[0];
        int bi = 0;
#pragma unroll
        for (int i = 1; i < kK; ++i) {
            const float v = p[i] + Tcol[i];
            const bool g = v > best;    // strict > => first-index argmax
            best = g ? v : best;
            bi   = g ? i : bi;
        }

        prev = best + emit;
        if (j < kK) bpb[(size_t)(t - 1) * kSlot + j] = (uint8_t)bi;
    }

    // final argmax over the 12 tag lanes (every lane computes it identically)
    float f[kK];
#pragma unroll
    for (int i = 0; i < kK; ++i) {
        f[i] = __int_as_float(
            __builtin_amdgcn_ds_bpermute((gbase + i) << 2,
                                         __float_as_int(prev)));
    }
    float best = f[0];
    int last = 0;
#pragma unroll
    for (int i = 1; i < kK; ++i) {
        const bool g = f[i] > best;
        best = g ? f[i] : best;
        last = g ? i : last;
    }

    __syncthreads();  // drain bp stores (vmcnt) before same-wave readback

    if (j == 0) {
        out[b] = best;
        float* paths = out + kB + (size_t)b * kT;
        paths[kT - 1] = (float)last;

        int tag = last;
        const uint32_t* w = (const uint32_t*)bpb;  // 3 dwords per slot
#pragma unroll 8
        for (int s = kT - 2; s >= 0; --s) {
            const uint32_t w0 = w[s * 3 + 0];
            const uint32_t w1 = w[s * 3 + 1];
            const uint32_t w2 = w[s * 3 + 2];
            const uint32_t d = (tag >= 8) ? w2 : ((tag >= 4) ? w1 : w0);
            tag = (int)((d >> ((tag & 3) * 8)) & 0xFF);
            paths[s] = (float)tag;
        }
    }
}

} // namespace

extern "C" void kernel_launch(void* const* d_in, const int* in_sizes, int n_in,
                              void* d_out, int out_size, void* d_ws, size_t ws_size,
                              hipStream_t stream) {
    const float* logits = (const float*)d_in[0];   // [8192, 512, 12] f32
    const float* trans  = (const float*)d_in[1];   // [12, 12] f32
    float* out = (float*)d_out;                    // 8192 + 8192*512 floats
    uint8_t* bp = (uint8_t*)d_ws;                  // needs 8192*511*12 = 50.2 MB

    const int threads = 256;
    const int blocks = (kB * 16) / threads;        // 512 blocks
    viterbi_fused<<<blocks, threads, 0, stream>>>(logits, trans, out, bp);
}

// Round 2
// 540.064 us; speedup vs baseline: 1.3369x; 1.3369x over previous
//
#include <hip/hip_runtime.h>
#include <stdint.h>

// Batched Viterbi decode: B=8192, T=512, K=12.
// 16 lanes per batch row (12 active tag-lanes, 4 pad). Forward recursion with
// ds_bpermute exchange; emissions software-pipelined 8 steps ahead so the
// loop-carried chain is only bpermute + depth-4 argmax tree. Backpointers
// packed 4 steps per dword: ws layout bpw[b][w][j], w in [0,128), j in [0,12).
// Backtrack fused (lane 0 per group), loads are tag-independent (prefetchable).
//
// Output = [scores: B floats][paths: B*T floats].

namespace {

constexpr int kB = 8192;
constexpr int kT = 512;
constexpr int kK = 12;
constexpr int kW = 128;   // ceil((T-1)/4) backpointer words per (b, j)

struct VI { float v; int i; };

__device__ __forceinline__ VI vmax(VI a, VI b) {
    // keep-left on >= : preserves first-index argmax through a balanced tree
    const bool l = a.v >= b.v;
    VI r;
    r.v = l ? a.v : b.v;
    r.i = l ? a.i : b.i;
    return r;
}

__global__ __launch_bounds__(256) void viterbi_fused(
    const float* __restrict__ logits,   // [B, T, K]
    const float* __restrict__ trans,    // [K, K]
    float* __restrict__ out,            // [B] scores + [B*T] paths
    uint32_t* __restrict__ bpw)         // [B, kW, kK]
{
    const int tid  = blockIdx.x * blockDim.x + threadIdx.x;
    const int b    = tid >> 4;
    const int j    = tid & 15;
    const int jeff = (j < kK) ? j : (kK - 1);
    const int lane = threadIdx.x & 63;
    const int gbase4 = (lane & 48) << 2;   // byte index of group base for bpermute

    // transitions column jeff: Tcol[i] = trans[i][jeff]
    float Tcol[kK];
#pragma unroll
    for (int i = 0; i < kK; ++i) Tcol[i] = trans[i * kK + jeff];

    const float* em = logits + (size_t)b * kT * kK;
    uint32_t* bpb = bpw + (size_t)b * kW * kK;

    float prev = em[jeff];              // t = 0

    // prefetch emissions for t = 1..8
    float ebuf[8];
#pragma unroll
    for (int u = 0; u < 8; ++u) ebuf[u] = em[(1 + u) * kK + jeff];

    uint32_t packed = 0;

    for (int tb = 1; tb <= 511; tb += 8) {
        // prefetch next chunk's emissions (t = tb+8 .. tb+15)
        float nbuf[8];
#pragma unroll
        for (int u = 0; u < 8; ++u) {
            const int tn = tb + 8 + u;
            nbuf[u] = (tn <= 511) ? em[tn * kK + jeff] : 0.0f;
        }

#pragma unroll
        for (int u = 0; u < 8; ++u) {
            const int t = tb + u;
            if (t <= 511) {
                // gather prev[0..11] from the group's tag lanes
                float p[kK];
#pragma unroll
                for (int i = 0; i < kK; ++i) {
                    p[i] = __int_as_float(
                        __builtin_amdgcn_ds_bpermute(gbase4 + (i << 2),
                                                     __float_as_int(prev)));
                }

                VI c[kK];
#pragma unroll
                for (int i = 0; i < kK; ++i) { c[i].v = p[i] + Tcol[i]; c[i].i = i; }

                // depth-4 first-index argmax tree
                VI w01 = vmax(c[0], c[1]),  w23 = vmax(c[2], c[3]);
                VI w45 = vmax(c[4], c[5]),  w67 = vmax(c[6], c[7]);
                VI w89 = vmax(c[8], c[9]),  wab = vmax(c[10], c[11]);
                VI w03 = vmax(w01, w23),    w47 = vmax(w45, w67);
                VI w8b = vmax(w89, wab);
                VI w07 = vmax(w03, w47);
                VI win = vmax(w07, w8b);

                prev = win.v + ebuf[u];

                // pack backpointer byte; step s = t-1, s&3 == u&3 (tb-1 ≡ 0 mod 8)
                packed |= ((uint32_t)win.i) << (8 * (u & 3));
                if ((u & 3) == 3) {
                    const int w = (t - 1) >> 2;
                    if (j < kK) bpb[(size_t)w * kK + j] = packed;
                    packed = 0;
                }
            }
        }

#pragma unroll
        for (int u = 0; u < 8; ++u) ebuf[u] = nbuf[u];
    }

    // tail word (steps 508..510 -> word 127, 511 % 4 == 3)
    if (j < kK) bpb[(size_t)(kW - 1) * kK + j] = packed;

    // final argmax over the 12 tag lanes
    VI f[kK];
#pragma unroll
    for (int i = 0; i < kK; ++i) {
        f[i].v = __int_as_float(
            __builtin_amdgcn_ds_bpermute(gbase4 + (i << 2),
                                         __float_as_int(prev)));
        f[i].i = i;
    }
    VI w01 = vmax(f[0], f[1]),  w23 = vmax(f[2], f[3]);
    VI w45 = vmax(f[4], f[5]),  w67 = vmax(f[6], f[7]);
    VI w89 = vmax(f[8], f[9]),  wab = vmax(f[10], f[11]);
    VI w03 = vmax(w01, w23),    w47 = vmax(w45, w67);
    VI w8b = vmax(w89, wab);
    VI w07 = vmax(w03, w47);
    VI win = vmax(w07, w8b);

    __syncthreads();  // drain backpointer stores before same-wave readback

    if (j == 0) {
        out[b] = win.v;
        float* paths = out + kB + (size_t)b * kT;
        paths[kT - 1] = (float)win.i;

        int tag = win.i;
        const uint4* r = (const uint4*)bpb;  // 3 x uint4 = 12 dwords per word-record
#pragma unroll 4
        for (int w = kW - 1; w >= 0; --w) {
            const uint4 q0 = r[w * 3 + 0];   // dwords j=0..3
            const uint4 q1 = r[w * 3 + 1];   // j=4..7
            const uint4 q2 = r[w * 3 + 2];   // j=8..11
            const int smax = (w == kW - 1) ? 510 : (w * 4 + 3);
#pragma unroll
            for (int d = 0; d < 4; ++d) {
                const int s = smax - ((w == kW - 1) ? (2 - d >= 0 ? 2 - d : -1)
                                                    : (3 - d));
                // simpler: iterate s from smax down to w*4
                (void)s;
            }
            // walk steps smax .. w*4 (descending)
            for (int s = smax; s >= w * 4; --s) {
                // select dword for current tag (bit-tree mux)
                const uint4 qa = (tag & 8) ? q2 : ((tag & 4) ? q1 : q0);
                uint32_t d0, d1;
                d0 = (tag & 1) ? qa.y : qa.x;
                d1 = (tag & 1) ? qa.w : qa.z;
                const uint32_t dw = (tag & 2) ? d1 : d0;
                tag = (int)((dw >> (8 * (s & 3))) & 0xFF);
                paths[s] = (float)tag;
            }
        }
    }
}

} // namespace

extern "C" void kernel_launch(void* const* d_in, const int* in_sizes, int n_in,
                              void* d_out, int out_size, void* d_ws, size_t ws_size,
                              hipStream_t stream) {
    const float* logits = (const float*)d_in[0];   // [8192, 512, 12] f32
    const float* trans  = (const float*)d_in[1];   // [12, 12] f32
    float* out = (float*)d_out;
    uint32_t* bpw = (uint32_t*)d_ws;               // 8192*128*12*4 = 50.3 MB

    const int threads = 256;
    const int blocks = (kB * 16) / threads;        // 512 blocks
    viterbi_fused<<<blocks, threads, 0, stream>>>(logits, trans, out, bpw);
}

// Round 3
// 499.718 us; speedup vs baseline: 1.4448x; 1.0807x over previous
//
#include <hip/hip_runtime.h>
#include <stdint.h>

// Batched Viterbi decode: B=8192, T=512, K=12.
// 16 lanes per batch row (12 tag-lanes + 4 pad), 4 rows per wave.
// Per-step exchange: ds_write_b32 + 3x ds_read_b128 through a per-group LDS
// row (wave-internal => LDS pipe in-order; wave_barrier() pins compiler order).
// Value chain: 12 adds -> v_max3 tree -> +emit. Argmax off-chain via
// descending equality scan (exact first-index, matches jnp.argmax on ties).
// Emissions software-pipelined one 8-step block ahead in NAMED scalar regs.
// Backpointers packed 4 steps/dword: bpw[b][w][j], w in [0,128).
// Output = [scores: B floats][paths: B*T floats].

namespace {

constexpr int kB = 8192;
constexpr int kT = 512;
constexpr int kK = 12;
constexpr int kW = 128;

__global__ __launch_bounds__(256) void viterbi_fused(
    const float* __restrict__ logits,   // [B, T, K]
    const float* __restrict__ trans,    // [K, K]
    float* __restrict__ out,            // [B] scores + [B*T] paths
    uint32_t* __restrict__ bpw)         // [B, kW, kK]
{
    __shared__ __align__(64) float xch[16][16];   // 16 groups x 16 floats

    const int tid = blockIdx.x * 256 + threadIdx.x;
    const int b   = tid >> 4;
    const int j   = threadIdx.x & 15;
    const int g   = threadIdx.x >> 4;             // group within block
    const int jeff = (j < kK) ? j : (kK - 1);

    float* __restrict__ xg = &xch[g][0];

    // transitions column jeff
    const float T0  = trans[0*kK+jeff],  T1  = trans[1*kK+jeff];
    const float T2  = trans[2*kK+jeff],  T3  = trans[3*kK+jeff];
    const float T4  = trans[4*kK+jeff],  T5  = trans[5*kK+jeff];
    const float T6  = trans[6*kK+jeff],  T7  = trans[7*kK+jeff];
    const float T8  = trans[8*kK+jeff],  T9  = trans[9*kK+jeff];
    const float T10 = trans[10*kK+jeff], T11 = trans[11*kK+jeff];

    const float* __restrict__ em = logits + (size_t)b * kT * kK + jeff;
    uint32_t* __restrict__ bpb = bpw + (size_t)b * kW * kK;

    float prev = em[0];

    // emissions for t = 1..8 in named regs
    float e0 = em[1*kK], e1 = em[2*kK], e2 = em[3*kK], e3 = em[4*kK];
    float e4 = em[5*kK], e5 = em[6*kK], e6 = em[7*kK], e7 = em[8*kK];

    uint32_t packed = 0;

#define EMLOAD(t) em[((t) < kT ? (t) : (kT - 1)) * kK]

#define STEP(K, WBASE, EMIT) do {                                            \
    xg[j] = prev;                                                            \
    __builtin_amdgcn_wave_barrier();                                         \
    const float4 Aq = *(const float4*)(xg + 0);                              \
    const float4 Bq = *(const float4*)(xg + 4);                              \
    const float4 Cq = *(const float4*)(xg + 8);                              \
    __builtin_amdgcn_wave_barrier();                                         \
    const float c0 = Aq.x + T0,  c1 = Aq.y + T1;                             \
    const float c2 = Aq.z + T2,  c3 = Aq.w + T3;                             \
    const float c4 = Bq.x + T4,  c5 = Bq.y + T5;                             \
    const float c6 = Bq.z + T6,  c7 = Bq.w + T7;                             \
    const float c8 = Cq.x + T8,  c9 = Cq.y + T9;                             \
    const float c10 = Cq.z + T10, c11 = Cq.w + T11;                          \
    const float m0 = fmaxf(fmaxf(c0, c1), c2);                               \
    const float m1 = fmaxf(fmaxf(c3, c4), c5);                               \
    const float m2 = fmaxf(fmaxf(c6, c7), c8);                               \
    const float m3 = fmaxf(fmaxf(c9, c10), c11);                             \
    const float best = fmaxf(fmaxf(m0, m1), fmaxf(m2, m3));                  \
    int bi = 11;                                                             \
    bi = (c10 == best) ? 10 : bi;  bi = (c9 == best) ? 9 : bi;               \
    bi = (c8  == best) ?  8 : bi;  bi = (c7 == best) ? 7 : bi;               \
    bi = (c6  == best) ?  6 : bi;  bi = (c5 == best) ? 5 : bi;               \
    bi = (c4  == best) ?  4 : bi;  bi = (c3 == best) ? 3 : bi;               \
    bi = (c2  == best) ?  2 : bi;  bi = (c1 == best) ? 1 : bi;               \
    bi = (c0  == best) ?  0 : bi;                                            \
    prev = best + (EMIT);                                                    \
    packed |= (uint32_t)bi << (8 * ((K) & 3));                               \
    if (((K) & 3) == 3) {                                                    \
        if (j < kK) bpb[(size_t)((WBASE) + ((K) >> 2)) * kK + j] = packed;   \
        packed = 0;                                                          \
    }                                                                        \
} while (0)

    // main: t = 1..504 in 63 guard-free blocks of 8
    for (int n = 0; n < 63; ++n) {
        const int tb = 8 * n + 1;
        const int w0 = 2 * n;
        // prefetch next block's emissions (t = tb+8 .. tb+15, clamped)
        const float f0 = EMLOAD(tb + 8),  f1 = EMLOAD(tb + 9);
        const float f2 = EMLOAD(tb + 10), f3 = EMLOAD(tb + 11);
        const float f4 = EMLOAD(tb + 12), f5 = EMLOAD(tb + 13);
        const float f6 = EMLOAD(tb + 14), f7 = EMLOAD(tb + 15);

        STEP(0, w0, e0); STEP(1, w0, e1); STEP(2, w0, e2); STEP(3, w0, e3);
        STEP(4, w0, e4); STEP(5, w0, e5); STEP(6, w0, e6); STEP(7, w0, e7);

        e0 = f0; e1 = f1; e2 = f2; e3 = f3;
        e4 = f4; e5 = f5; e6 = f6; e7 = f7;
    }

    // tail: t = 505..511 (e0..e6 hold em[505..511]); steps s = 504..510
    STEP(0, 126, e0); STEP(1, 126, e1); STEP(2, 126, e2); STEP(3, 126, e3);
    STEP(4, 126, e4); STEP(5, 126, e5); STEP(6, 126, e6);
    if (j < kK) bpb[(size_t)127 * kK + j] = packed;   // flush word 127 (3 bytes)

#undef STEP
#undef EMLOAD

    // final argmax over tags (first-index on ties)
    xg[j] = prev;
    __builtin_amdgcn_wave_barrier();
    const float4 Aq = *(const float4*)(xg + 0);
    const float4 Bq = *(const float4*)(xg + 4);
    const float4 Cq = *(const float4*)(xg + 8);
    __builtin_amdgcn_wave_barrier();
    const float v0 = Aq.x, v1 = Aq.y, v2 = Aq.z, v3 = Aq.w;
    const float v4 = Bq.x, v5 = Bq.y, v6 = Bq.z, v7 = Bq.w;
    const float v8 = Cq.x, v9 = Cq.y, v10 = Cq.z, v11 = Cq.w;
    const float n0 = fmaxf(fmaxf(v0, v1), v2);
    const float n1 = fmaxf(fmaxf(v3, v4), v5);
    const float n2 = fmaxf(fmaxf(v6, v7), v8);
    const float n3 = fmaxf(fmaxf(v9, v10), v11);
    const float best = fmaxf(fmaxf(n0, n1), fmaxf(n2, n3));
    int last = 11;
    last = (v10 == best) ? 10 : last;  last = (v9 == best) ? 9 : last;
    last = (v8  == best) ?  8 : last;  last = (v7 == best) ? 7 : last;
    last = (v6  == best) ?  6 : last;  last = (v5 == best) ? 5 : last;
    last = (v4  == best) ?  4 : last;  last = (v3 == best) ? 3 : last;
    last = (v2  == best) ?  2 : last;  last = (v1 == best) ? 1 : last;
    last = (v0  == best) ?  0 : last;

    __syncthreads();  // drain backpointer stores before same-wave readback

    if (j == 0) {
        out[b] = best;
        float* __restrict__ paths = out + kB + (size_t)b * kT;
        paths[kT - 1] = (float)last;

        int tag = last;
        const uint4* __restrict__ r = (const uint4*)bpb;  // 3 uint4 per word
#pragma unroll 2
        for (int w = kW - 1; w >= 0; --w) {
            const uint4 q0 = r[w * 3 + 0];   // dwords j = 0..3
            const uint4 q1 = r[w * 3 + 1];   // j = 4..7
            const uint4 q2 = r[w * 3 + 2];   // j = 8..11
            const int smax = (w == kW - 1) ? 510 : (w * 4 + 3);
            for (int s = smax; s >= w * 4; --s) {
                const uint32_t ax = (tag & 8) ? q2.x : ((tag & 4) ? q1.x : q0.x);
                const uint32_t ay = (tag & 8) ? q2.y : ((tag & 4) ? q1.y : q0.y);
                const uint32_t az = (tag & 8) ? q2.z : ((tag & 4) ? q1.z : q0.z);
                const uint32_t aw = (tag & 8) ? q2.w : ((tag & 4) ? q1.w : q0.w);
                const uint32_t lo = (tag & 1) ? ay : ax;
                const uint32_t hi = (tag & 1) ? aw : az;
                const uint32_t dw = (tag & 2) ? hi : lo;
                tag = (int)((dw >> (8 * (s & 3))) & 0xFF);
                paths[s] = (float)tag;
            }
        }
    }
}

} // namespace

extern "C" void kernel_launch(void* const* d_in, const int* in_sizes, int n_in,
                              void* d_out, int out_size, void* d_ws, size_t ws_size,
                              hipStream_t stream) {
    const float* logits = (const float*)d_in[0];   // [8192, 512, 12] f32
    const float* trans  = (const float*)d_in[1];   // [12, 12] f32
    float* out = (float*)d_out;
    uint32_t* bpw = (uint32_t*)d_ws;               // 8192*128*12*4 = 50.3 MB

    const int threads = 256;
    const int blocks = (kB * 16) / threads;        // 512 blocks
    viterbi_fused<<<blocks, threads, 0, stream>>>(logits, trans, out, bpw);
}